// Round 1
// baseline (4498.599 us; speedup 1.0000x reference)
//
#include <hip/hip_runtime.h>
#include <math.h>

#define T_SEQ   1536
#define NB      2
#define MROWS   3072          // NB*T_SEQ
#define DMODEL  512
#define NHEADS  8
#define DHEAD   64
#define DFF     2048
#define DMOTION 256
#define NLAYERS 6
#define PERIODN 15
#define CTXF    10
#define THRW    128
#define DIN     262           // D_MOTION + 5 + 1
#define LDAIN   272           // padded to 17*16 so fp32 float4 K-loop never overruns

// ---------------------------------------------------------------------------
// Positional-encoding table: only 15 distinct rows (pos = t mod 15).
// ---------------------------------------------------------------------------
__global__ __launch_bounds__(256) void pe_k(float* __restrict__ pe) {
    int idx = blockIdx.x * 256 + threadIdx.x;
    if (idx >= PERIODN * DMODEL) return;
    int p = idx / DMODEL;
    int c = idx % DMODEL;
    int j = (c < DMODEL / 2) ? c : (c - DMODEL / 2);
    float div = __expf(-logf(10000.0f) * (2.0f * (float)j) / (float)DMODEL);
    float ang = (float)p * div;
    pe[idx] = (c < DMODEL / 2) ? sinf(ang) : cosf(ang);
}

// ---------------------------------------------------------------------------
// Build encoder input h = [motion*mask, traj, mask, 0-pad] with lda=272,
// and write the mask output (second tuple element).
// ---------------------------------------------------------------------------
__global__ __launch_bounds__(256) void build_k(const float* __restrict__ motion,
                                               const float* __restrict__ traj,
                                               float* __restrict__ hin,
                                               float* __restrict__ mask_out) {
    int idx = blockIdx.x * 256 + threadIdx.x;
    if (idx >= MROWS * LDAIN) return;
    int row = idx / LDAIN;
    int c   = idx % LDAIN;
    int t   = row % T_SEQ;
    float mv = (t < CTXF || t == T_SEQ - 1) ? 1.0f : 0.0f;
    float val;
    if (c < DMOTION)            val = motion[(size_t)row * DMOTION + c] * mv;
    else if (c < DMOTION + 5)   val = traj[(size_t)row * 5 + (c - DMOTION)];
    else if (c == DMOTION + 5)  val = mv;
    else                        val = 0.0f;
    hin[idx] = val;
    if (c == 0) mask_out[row] = mv;
}

// ---------------------------------------------------------------------------
// Tiled fp32 GEMM: C[M,N] = epilogue(A[M,K(lda)] @ W[K,N] + bias)
// ACT: 0 none, 1 leaky(0.01), 2 relu.  PE adds pe15[(r%T)%15].  RES adds res.
// 64x64 tile, 256 threads, 4x4 micro-tile, KT=16.
// ---------------------------------------------------------------------------
template <int ACT, bool RES, bool PE>
__global__ __launch_bounds__(256)
void gemm_k(const float* __restrict__ A, int lda,
            const float* __restrict__ W, const float* __restrict__ bias,
            const float* __restrict__ res, const float* __restrict__ pe15,
            float* __restrict__ C, int N, int K) {
    __shared__ float As[64][17];
    __shared__ float Bs[16][68];
    const int tid = threadIdx.x;
    const int tx = tid & 15, ty = tid >> 4;
    const int row0 = blockIdx.y * 64;
    const int col0 = blockIdx.x * 64;

    const int arow = tid >> 2;            // 0..63
    const int akk  = (tid & 3) * 4;       // 0,4,8,12
    const int brow = tid >> 4;            // 0..15
    const int bcol = (tid & 15) * 4;      // 0..60

    float acc[4][4] = {};
    const int ktiles = (K + 15) >> 4;

    for (int kt = 0; kt < ktiles; ++kt) {
        const int k0 = kt << 4;
        // A rows always valid (M=3072 % 64 == 0); lda padded so k reads valid.
        float4 av = *(const float4*)&A[(size_t)(row0 + arow) * lda + k0 + akk];
        As[arow][akk + 0] = av.x; As[arow][akk + 1] = av.y;
        As[arow][akk + 2] = av.z; As[arow][akk + 3] = av.w;
        float4 bv;
        if (k0 + brow < K) bv = *(const float4*)&W[(size_t)(k0 + brow) * N + col0 + bcol];
        else               bv = make_float4(0.f, 0.f, 0.f, 0.f);
        Bs[brow][bcol + 0] = bv.x; Bs[brow][bcol + 1] = bv.y;
        Bs[brow][bcol + 2] = bv.z; Bs[brow][bcol + 3] = bv.w;
        __syncthreads();
#pragma unroll
        for (int kk = 0; kk < 16; ++kk) {
            float a0 = As[ty * 4 + 0][kk];
            float a1 = As[ty * 4 + 1][kk];
            float a2 = As[ty * 4 + 2][kk];
            float a3 = As[ty * 4 + 3][kk];
            float4 b = *(const float4*)&Bs[kk][tx * 4];
            acc[0][0] += a0 * b.x; acc[0][1] += a0 * b.y; acc[0][2] += a0 * b.z; acc[0][3] += a0 * b.w;
            acc[1][0] += a1 * b.x; acc[1][1] += a1 * b.y; acc[1][2] += a1 * b.z; acc[1][3] += a1 * b.w;
            acc[2][0] += a2 * b.x; acc[2][1] += a2 * b.y; acc[2][2] += a2 * b.z; acc[2][3] += a2 * b.w;
            acc[3][0] += a3 * b.x; acc[3][1] += a3 * b.y; acc[3][2] += a3 * b.z; acc[3][3] += a3 * b.w;
        }
        __syncthreads();
    }

#pragma unroll
    for (int i = 0; i < 4; ++i) {
        const int r = row0 + ty * 4 + i;
        const int c = col0 + tx * 4;
        float4 v;
        v.x = acc[i][0] + bias[c + 0];
        v.y = acc[i][1] + bias[c + 1];
        v.z = acc[i][2] + bias[c + 2];
        v.w = acc[i][3] + bias[c + 3];
        if (ACT == 1) {
            v.x = v.x >= 0.f ? v.x : 0.01f * v.x;
            v.y = v.y >= 0.f ? v.y : 0.01f * v.y;
            v.z = v.z >= 0.f ? v.z : 0.01f * v.z;
            v.w = v.w >= 0.f ? v.w : 0.01f * v.w;
        } else if (ACT == 2) {
            v.x = fmaxf(v.x, 0.f); v.y = fmaxf(v.y, 0.f);
            v.z = fmaxf(v.z, 0.f); v.w = fmaxf(v.w, 0.f);
        }
        if (PE) {
            const int p = (r % T_SEQ) % PERIODN;
            const float* pr = pe15 + p * DMODEL + c;
            v.x += pr[0]; v.y += pr[1]; v.z += pr[2]; v.w += pr[3];
        }
        if (RES) {
            float4 rv = *(const float4*)&res[(size_t)r * N + c];
            v.x += rv.x; v.y += rv.y; v.z += rv.z; v.w += rv.w;
        }
        *(float4*)&C[(size_t)r * N + c] = v;
    }
}

// ---------------------------------------------------------------------------
// LayerNorm: one wave per row of 512.
// ---------------------------------------------------------------------------
__global__ __launch_bounds__(256)
void ln_k(const float* __restrict__ X, const float* __restrict__ g,
          const float* __restrict__ b, float* __restrict__ Y) {
    const int wid = threadIdx.x >> 6, lane = threadIdx.x & 63;
    const int row = blockIdx.x * 4 + wid;
    const float* x = X + (size_t)row * DMODEL;
    float v[8];
    float s = 0.f;
#pragma unroll
    for (int j = 0; j < 8; ++j) { v[j] = x[lane + 64 * j]; s += v[j]; }
#pragma unroll
    for (int o = 32; o; o >>= 1) s += __shfl_xor(s, o);
    const float mean = s * (1.0f / DMODEL);
    float vs = 0.f;
#pragma unroll
    for (int j = 0; j < 8; ++j) { float d = v[j] - mean; vs += d * d; }
#pragma unroll
    for (int o = 32; o; o >>= 1) vs += __shfl_xor(vs, o);
    const float inv = rsqrtf(vs * (1.0f / DMODEL) + 1e-5f);
    float* y = Y + (size_t)row * DMODEL;
#pragma unroll
    for (int j = 0; j < 8; ++j) {
        const int c = lane + 64 * j;
        y[c] = (v[j] - mean) * inv * g[c] + b[c];
    }
}

// ---------------------------------------------------------------------------
// Per-(b,h) mean of V over all T keys (fully-masked-row fallback:
// softmax of an all-(-1e9) row is uniform 1/T over every key).
// ---------------------------------------------------------------------------
__global__ __launch_bounds__(256)
void vmean_k(const float* __restrict__ V, float* __restrict__ vm) {
    __shared__ float red[4][64];
    const int bh = blockIdx.x;            // 0..15
    const int b = bh >> 3, h = bh & 7;
    const int lane = threadIdx.x & 63, qd = threadIdx.x >> 6;
    float s = 0.f;
    for (int t = qd; t < T_SEQ; t += 4)
        s += V[((size_t)(b * T_SEQ + t)) * DMODEL + h * DHEAD + lane];
    red[qd][lane] = s;
    __syncthreads();
    if (qd == 0) {
        float tot = red[0][lane] + red[1][lane] + red[2][lane] + red[3][lane];
        vm[bh * DHEAD + lane] = tot * (1.0f / T_SEQ);
    }
}

// ---------------------------------------------------------------------------
// Attention for one layer. Allowed keys for query q:
//   |q-k| <= 128  AND  (k < lo  OR  k >= hi)       (lo=10+128i, hi=1535-128i)
// Two disjoint intervals. Fully-masked rows -> vmean. Bias = -(|q-k|/15).
// One wave per (b,h,q) row; 4 waves per block.
// ---------------------------------------------------------------------------
__global__ __launch_bounds__(256)
void attn_k(const float* __restrict__ Q, const float* __restrict__ K,
            const float* __restrict__ V, const float* __restrict__ vm,
            float* __restrict__ O, int lo, int hi) {
    __shared__ float qs[4][64];
    __shared__ float ps[4][260];
    const int lane = threadIdx.x & 63, wid = threadIdx.x >> 6;
    const int h = blockIdx.y, b = blockIdx.z;
    const int qrow = blockIdx.x * 4 + wid;
    const size_t base = (size_t)(b * T_SEQ) * DMODEL + h * DHEAD;

    qs[wid][lane] = Q[base + (size_t)qrow * DMODEL + lane];
    __syncthreads();

    const int w0 = max(0, qrow - THRW), w1 = min(T_SEQ - 1, qrow + THRW);
    const int a0 = w0, a1 = min(w1, lo - 1);
    const int b0 = max(w0, hi), b1 = w1;
    const int n1 = max(0, a1 - a0 + 1);
    const int n2 = max(0, b1 - b0 + 1);
    const int nt = n1 + n2;

    float mx = -3.0e38f;
    for (int j = lane; j < nt; j += 64) {
        const int key = (j < n1) ? (a0 + j) : (b0 + (j - n1));
        const float* kr = K + base + (size_t)key * DMODEL;
        float dot = 0.f;
#pragma unroll
        for (int d = 0; d < 64; ++d) dot += qs[wid][d] * kr[d];
        const int dist = abs(qrow - key);
        const float sc = dot * 0.125f - (float)(dist / PERIODN);
        ps[wid][j] = sc;
        mx = fmaxf(mx, sc);
    }
#pragma unroll
    for (int o = 32; o; o >>= 1) mx = fmaxf(mx, __shfl_xor(mx, o));

    float sum = 0.f;
    for (int j = lane; j < nt; j += 64) {
        const float e = __expf(ps[wid][j] - mx);
        ps[wid][j] = e;
        sum += e;
    }
#pragma unroll
    for (int o = 32; o; o >>= 1) sum += __shfl_xor(sum, o);

    float outv;
    if (nt == 0) {
        outv = vm[(b * NHEADS + h) * DHEAD + lane];
    } else {
        const float inv = 1.0f / sum;
        float acc = 0.f;
        for (int key = a0; key <= a1; ++key)
            acc += ps[wid][key - a0] * V[base + (size_t)key * DMODEL + lane];
        for (int key = b0; key <= b1; ++key)
            acc += ps[wid][n1 + key - b0] * V[base + (size_t)key * DMODEL + lane];
        outv = acc * inv;
    }
    O[base + (size_t)qrow * DMODEL + lane] = outv;
}

// ---------------------------------------------------------------------------
// Final blend: out = motion*mask + xdec*(1-mask)
// ---------------------------------------------------------------------------
__global__ __launch_bounds__(256)
void final_k(const float* __restrict__ motion, const float* __restrict__ xdec,
             float* __restrict__ out) {
    int idx = blockIdx.x * 256 + threadIdx.x;
    if (idx >= MROWS * DMOTION) return;
    const int row = idx >> 8;             // DMOTION == 256
    const int t = row % T_SEQ;
    const float mv = (t < CTXF || t == T_SEQ - 1) ? 1.0f : 0.0f;
    out[idx] = motion[idx] * mv + xdec[idx] * (1.0f - mv);
}

// ---------------------------------------------------------------------------
extern "C" void kernel_launch(void* const* d_in, const int* in_sizes, int n_in,
                              void* d_out, int out_size, void* d_ws, size_t ws_size,
                              hipStream_t stream) {
    const float* motion = (const float*)d_in[0];
    const float* traj   = (const float*)d_in[1];
    const float* me_w1  = (const float*)d_in[2];
    const float* me_b1  = (const float*)d_in[3];
    const float* me_w2  = (const float*)d_in[4];
    const float* me_b2  = (const float*)d_in[5];
    const float* wq = (const float*)d_in[6];
    const float* bq = (const float*)d_in[7];
    const float* wk = (const float*)d_in[8];
    const float* bk = (const float*)d_in[9];
    const float* wv = (const float*)d_in[10];
    const float* bv = (const float*)d_in[11];
    const float* wo = (const float*)d_in[12];
    const float* bo = (const float*)d_in[13];
    const float* ln1_g = (const float*)d_in[14];
    const float* ln1_b = (const float*)d_in[15];
    const float* ffn_w1 = (const float*)d_in[16];
    const float* ffn_b1 = (const float*)d_in[17];
    const float* ffn_w2 = (const float*)d_in[18];
    const float* ffn_b2 = (const float*)d_in[19];
    const float* ln2_g = (const float*)d_in[20];
    const float* ln2_b = (const float*)d_in[21];
    const float* fln_g = (const float*)d_in[22];
    const float* fln_b = (const float*)d_in[23];
    const float* dec_w1 = (const float*)d_in[24];
    const float* dec_b1 = (const float*)d_in[25];
    const float* dec_w2 = (const float*)d_in[26];
    const float* dec_b2 = (const float*)d_in[27];

    float* out = (float*)d_out;                       // [786432] + mask [3072]
    float* mask_out = out + (size_t)MROWS * DMOTION;

    float* w = (float*)d_ws;
    size_t o = 0;
    float* hin = w + o; o += (size_t)MROWS * LDAIN;   // encoder input, padded
    float* x   = w + o; o += (size_t)MROWS * DMODEL;  // residual stream
    float* h   = w + o; o += (size_t)MROWS * DMODEL;  // LN output / temps
    float* q   = w + o; o += (size_t)MROWS * DMODEL;
    float* k   = w + o; o += (size_t)MROWS * DMODEL;  // also reused as xdec
    float* v   = w + o; o += (size_t)MROWS * DMODEL;
    float* att = w + o; o += (size_t)MROWS * DMODEL;  // also reused as dec1
    float* ff  = w + o; o += (size_t)MROWS * DFF;
    float* pe15 = w + o; o += (size_t)PERIODN * DMODEL;
    float* vm   = w + o; o += (size_t)NB * NHEADS * DHEAD;

    const dim3 blk(256);
    const dim3 g512(DMODEL / 64, MROWS / 64);
    const dim3 gff(DFF / 64, MROWS / 64);
    const dim3 g256(DMOTION / 64, MROWS / 64);
    const dim3 gattn(T_SEQ / 4, NHEADS, NB);

    pe_k<<<(PERIODN * DMODEL + 255) / 256, blk, 0, stream>>>(pe15);
    build_k<<<(MROWS * LDAIN + 255) / 256, blk, 0, stream>>>(motion, traj, hin, mask_out);

    // motion encoder
    gemm_k<1, false, false><<<g512, blk, 0, stream>>>(hin, LDAIN, me_w1, me_b1, nullptr, nullptr, h, DMODEL, DIN);
    gemm_k<1, false, true ><<<g512, blk, 0, stream>>>(h, DMODEL, me_w2, me_b2, nullptr, pe15, x, DMODEL, DMODEL);

    for (int i = 0; i < NLAYERS; ++i) {
        const float* wqi = wq + (size_t)i * DMODEL * DMODEL;
        const float* wki = wk + (size_t)i * DMODEL * DMODEL;
        const float* wvi = wv + (size_t)i * DMODEL * DMODEL;
        const float* woi = wo + (size_t)i * DMODEL * DMODEL;
        const int lo = CTXF + THRW * i;          // allowed cols: k < lo or k >= hi
        const int hi = (T_SEQ - 1) - THRW * i;

        ln_k<<<MROWS / 4, blk, 0, stream>>>(x, ln1_g + i * DMODEL, ln1_b + i * DMODEL, h);
        gemm_k<0, false, false><<<g512, blk, 0, stream>>>(h, DMODEL, wqi, bq + i * DMODEL, nullptr, nullptr, q, DMODEL, DMODEL);
        gemm_k<0, false, false><<<g512, blk, 0, stream>>>(h, DMODEL, wki, bk + i * DMODEL, nullptr, nullptr, k, DMODEL, DMODEL);
        gemm_k<0, false, false><<<g512, blk, 0, stream>>>(h, DMODEL, wvi, bv + i * DMODEL, nullptr, nullptr, v, DMODEL, DMODEL);
        vmean_k<<<NB * NHEADS, blk, 0, stream>>>(v, vm);
        attn_k<<<gattn, blk, 0, stream>>>(q, k, v, vm, att, lo, hi);
        gemm_k<0, true, false><<<g512, blk, 0, stream>>>(att, DMODEL, woi, bo + i * DMODEL, x, nullptr, x, DMODEL, DMODEL);

        ln_k<<<MROWS / 4, blk, 0, stream>>>(x, ln2_g + i * DMODEL, ln2_b + i * DMODEL, h);
        gemm_k<2, false, false><<<gff, blk, 0, stream>>>(h, DMODEL, ffn_w1 + (size_t)i * DMODEL * DFF, ffn_b1 + i * DFF, nullptr, nullptr, ff, DFF, DMODEL);
        gemm_k<0, true, false><<<g512, blk, 0, stream>>>(ff, DFF, ffn_w2 + (size_t)i * DFF * DMODEL, ffn_b2 + i * DMODEL, x, nullptr, x, DMODEL, DFF);
    }

    // decoder
    ln_k<<<MROWS / 4, blk, 0, stream>>>(x, fln_g, fln_b, h);
    gemm_k<1, false, false><<<g512, blk, 0, stream>>>(h, DMODEL, dec_w1, dec_b1, nullptr, nullptr, att, DMODEL, DMODEL);
    gemm_k<0, false, false><<<g256, blk, 0, stream>>>(att, DMODEL, dec_w2, dec_b2, nullptr, nullptr, k, DMOTION, DMODEL);

    final_k<<<(MROWS * DMOTION + 255) / 256, blk, 0, stream>>>(motion, k, out);
}

// Round 2
// 1942.614 us; speedup vs baseline: 2.3157x; 2.3157x over previous
//
#include <hip/hip_runtime.h>
#include <math.h>

typedef unsigned short ushort_t;
typedef unsigned int uint_t;
typedef __bf16 bf16x4 __attribute__((ext_vector_type(4)));
typedef __bf16 bf16x8 __attribute__((ext_vector_type(8)));
typedef float f32x4 __attribute__((ext_vector_type(4)));

#define T_SEQ   1536
#define NB      2
#define MROWS   3072
#define DMODEL  512
#define NHEADS  8
#define DHEAD   64
#define DFF     2048
#define DMOTION 256
#define NLAYERS 6
#define PERIODN 15
#define CTXF    10
#define THRW    128
#define KIN     288           // 262 zero-padded to multiple of 32

__device__ __forceinline__ float bf2f(ushort_t u) { return __uint_as_float((uint_t)u << 16); }
__device__ __forceinline__ ushort_t f2bf(float f) {
    uint_t x = __float_as_uint(f);
    return (ushort_t)((x + 0x7fffu + ((x >> 16) & 1u)) >> 16);   // RNE
}

// ---------------------------------------------------------------------------
// PE table (15 distinct rows)
// ---------------------------------------------------------------------------
__global__ __launch_bounds__(256) void pe_k(float* __restrict__ pe) {
    int idx = blockIdx.x * 256 + threadIdx.x;
    if (idx >= PERIODN * DMODEL) return;
    int p = idx / DMODEL, c = idx % DMODEL;
    int j = (c < DMODEL / 2) ? c : (c - DMODEL / 2);
    float div = __expf(-logf(10000.0f) * (2.0f * (float)j) / (float)DMODEL);
    float ang = (float)p * div;
    pe[idx] = (c < DMODEL / 2) ? sinf(ang) : cosf(ang);
}

// ---------------------------------------------------------------------------
// Encoder input (bf16, K padded to 288) + mask output
// ---------------------------------------------------------------------------
__global__ __launch_bounds__(256) void build_k(const float* __restrict__ motion,
                                               const float* __restrict__ traj,
                                               ushort_t* __restrict__ hin,
                                               float* __restrict__ mask_out) {
    int idx = blockIdx.x * 256 + threadIdx.x;
    if (idx >= MROWS * KIN) return;
    int row = idx / KIN, c = idx % KIN;
    int t = row % T_SEQ;
    float mv = (t < CTXF || t == T_SEQ - 1) ? 1.0f : 0.0f;
    float val;
    if (c < DMOTION)            val = motion[(size_t)row * DMOTION + c] * mv;
    else if (c < DMOTION + 5)   val = traj[(size_t)row * 5 + (c - DMOTION)];
    else if (c == DMOTION + 5)  val = mv;
    else                        val = 0.0f;
    hin[idx] = f2bf(val);
    if (c == 0) mask_out[row] = mv;
}

// ---------------------------------------------------------------------------
// Transpose-convert: src f32 [K][N] -> dst bf16 [N][Kpad] (zero pad k>=K).
// Batched via blockIdx.z with strides.
// ---------------------------------------------------------------------------
__global__ __launch_bounds__(256)
void tconv_k(const float* __restrict__ src, size_t sstride,
             ushort_t* __restrict__ dst, size_t dstride,
             int K, int N, int Kpad) {
    __shared__ float t[32][33];
    src += (size_t)blockIdx.z * sstride;
    dst += (size_t)blockIdx.z * dstride;
    const int kb = blockIdx.y * 32, nb = blockIdx.x * 32;
    const int tx = threadIdx.x & 31, ty = threadIdx.x >> 5;
#pragma unroll
    for (int i = 0; i < 4; ++i) {
        int k = kb + ty + i * 8, n = nb + tx;
        t[ty + i * 8][tx] = (k < K && n < N) ? src[(size_t)k * N + n] : 0.0f;
    }
    __syncthreads();
#pragma unroll
    for (int i = 0; i < 4; ++i) {
        int n = nb + ty + i * 8, kk = kb + tx;
        if (n < N && kk < Kpad) dst[(size_t)n * Kpad + kk] = f2bf(t[tx][ty + i * 8]);
    }
}

// QKV concat transpose: z = layer*3+seg; dst = qkvt[l][seg*512 + n][k]
__global__ __launch_bounds__(256)
void tconv_qkv_k(const float* __restrict__ wq, const float* __restrict__ wk,
                 const float* __restrict__ wv, ushort_t* __restrict__ qkvt) {
    __shared__ float t[32][33];
    const int z = blockIdx.z, s = z % 3, l = z / 3;
    const float* src = (s == 0 ? wq : s == 1 ? wk : wv) + (size_t)l * DMODEL * DMODEL;
    ushort_t* dst = qkvt + (size_t)z * DMODEL * DMODEL;
    const int kb = blockIdx.y * 32, nb = blockIdx.x * 32;
    const int tx = threadIdx.x & 31, ty = threadIdx.x >> 5;
#pragma unroll
    for (int i = 0; i < 4; ++i)
        t[ty + i * 8][tx] = src[(size_t)(kb + ty + i * 8) * DMODEL + nb + tx];
    __syncthreads();
#pragma unroll
    for (int i = 0; i < 4; ++i)
        dst[(size_t)(nb + ty + i * 8) * DMODEL + kb + tx] = f2bf(t[tx][ty + i * 8]);
}

__global__ __launch_bounds__(256)
void bcat_k(const float* __restrict__ bq, const float* __restrict__ bk,
            const float* __restrict__ bv, float* __restrict__ bqkv) {
    int idx = blockIdx.x * 256 + threadIdx.x;
    if (idx >= NLAYERS * 3 * DMODEL) return;
    int l = idx / (3 * DMODEL), n = idx % (3 * DMODEL);
    int s = n >> 9, c = n & 511;
    const float* b = (s == 0 ? bq : s == 1 ? bk : bv);
    bqkv[idx] = b[l * DMODEL + c];
}

// ---------------------------------------------------------------------------
// bf16 MFMA GEMM: C[M,N] = epi(A[M,K] @ Wt[N,K]^T + bias)
// 128x128 tile, 4 waves (2x2), 4x4 16x16x32 fragments per wave, BK=32.
// LDS rows padded to 40 elems (80 B) -> row-strided ds_read_b64 is ~2-way.
// ACT: 0 none, 1 leaky, 2 relu. RES adds f32 res. PE adds pe table. OUTBF.
// ---------------------------------------------------------------------------
#define LDT 40
template <int ACT, bool RES, bool PE, bool OUTBF>
__global__ __launch_bounds__(256)
void mgemm_k(const ushort_t* __restrict__ A, int K,
             const ushort_t* __restrict__ Wt,
             const float* __restrict__ bias,
             const float* __restrict__ res,
             const float* __restrict__ pe15,
             void* __restrict__ Cout, int N) {
    __shared__ ushort_t As[128 * LDT];
    __shared__ ushort_t Bs[128 * LDT];
    const int tid = threadIdx.x;
    const int lane = tid & 63, wid = tid >> 6;
    const int wr = wid >> 1, wc = wid & 1;
    const int m0 = blockIdx.y * 128, n0 = blockIdx.x * 128;
    const int srow = tid >> 2, schunk = tid & 3;           // 64 rows x 4 chunks of 16B
    const int l4 = lane >> 4, l15 = lane & 15;

    f32x4 acc[4][4];
#pragma unroll
    for (int m = 0; m < 4; ++m)
#pragma unroll
        for (int n = 0; n < 4; ++n) acc[m][n] = (f32x4){0.f, 0.f, 0.f, 0.f};

    for (int k0 = 0; k0 < K; k0 += 32) {
        const uint4 av0 = *(const uint4*)(A  + (size_t)(m0 + srow)      * K + k0 + schunk * 8);
        const uint4 av1 = *(const uint4*)(A  + (size_t)(m0 + 64 + srow) * K + k0 + schunk * 8);
        const uint4 bv0 = *(const uint4*)(Wt + (size_t)(n0 + srow)      * K + k0 + schunk * 8);
        const uint4 bv1 = *(const uint4*)(Wt + (size_t)(n0 + 64 + srow) * K + k0 + schunk * 8);
        __syncthreads();
        *(uint4*)&As[srow * LDT + schunk * 8]        = av0;
        *(uint4*)&As[(64 + srow) * LDT + schunk * 8] = av1;
        *(uint4*)&Bs[srow * LDT + schunk * 8]        = bv0;
        *(uint4*)&Bs[(64 + srow) * LDT + schunk * 8] = bv1;
        __syncthreads();

        bf16x8 af[4], bfr[4];
#pragma unroll
        for (int m = 0; m < 4; ++m) {
            const int r = wr * 64 + m * 16 + l15;
            bf16x4 lo = *(const bf16x4*)&As[r * LDT + l4 * 4];
            bf16x4 hi = *(const bf16x4*)&As[r * LDT + 16 + l4 * 4];
            af[m] = __builtin_shufflevector(lo, hi, 0, 1, 2, 3, 4, 5, 6, 7);
        }
#pragma unroll
        for (int n = 0; n < 4; ++n) {
            const int r = wc * 64 + n * 16 + l15;
            bf16x4 lo = *(const bf16x4*)&Bs[r * LDT + l4 * 4];
            bf16x4 hi = *(const bf16x4*)&Bs[r * LDT + 16 + l4 * 4];
            bfr[n] = __builtin_shufflevector(lo, hi, 0, 1, 2, 3, 4, 5, 6, 7);
        }
#pragma unroll
        for (int m = 0; m < 4; ++m)
#pragma unroll
            for (int n = 0; n < 4; ++n)
                acc[m][n] = __builtin_amdgcn_mfma_f32_16x16x32_bf16(af[m], bfr[n], acc[m][n], 0, 0, 0);
    }

#pragma unroll
    for (int m = 0; m < 4; ++m)
#pragma unroll
        for (int n = 0; n < 4; ++n) {
            const int gcol = n0 + wc * 64 + n * 16 + l15;
            const float bc = bias[gcol];
#pragma unroll
            for (int r = 0; r < 4; ++r) {
                const int grow = m0 + wr * 64 + m * 16 + l4 * 4 + r;
                float v = acc[m][n][r] + bc;
                if (ACT == 1) v = v >= 0.f ? v : 0.01f * v;
                else if (ACT == 2) v = fmaxf(v, 0.f);
                if (PE) v += pe15[((grow % T_SEQ) % PERIODN) * DMODEL + gcol];
                if (RES) v += res[(size_t)grow * N + gcol];
                if (OUTBF) ((ushort_t*)Cout)[(size_t)grow * N + gcol] = f2bf(v);
                else       ((float*)Cout)[(size_t)grow * N + gcol] = v;
            }
        }
}

// ---------------------------------------------------------------------------
// LayerNorm: f32 in, bf16 out. One wave per row.
// ---------------------------------------------------------------------------
__global__ __launch_bounds__(256)
void ln_k(const float* __restrict__ X, const float* __restrict__ g,
          const float* __restrict__ b, ushort_t* __restrict__ Y) {
    const int wid = threadIdx.x >> 6, lane = threadIdx.x & 63;
    const int row = blockIdx.x * 4 + wid;
    const float* x = X + (size_t)row * DMODEL;
    float v[8], s = 0.f;
#pragma unroll
    for (int j = 0; j < 8; ++j) { v[j] = x[lane + 64 * j]; s += v[j]; }
#pragma unroll
    for (int o = 32; o; o >>= 1) s += __shfl_xor(s, o);
    const float mean = s * (1.0f / DMODEL);
    float vs = 0.f;
#pragma unroll
    for (int j = 0; j < 8; ++j) { float d = v[j] - mean; vs += d * d; }
#pragma unroll
    for (int o = 32; o; o >>= 1) vs += __shfl_xor(vs, o);
    const float inv = rsqrtf(vs * (1.0f / DMODEL) + 1e-5f);
    ushort_t* y = Y + (size_t)row * DMODEL;
#pragma unroll
    for (int j = 0; j < 8; ++j) {
        const int c = lane + 64 * j;
        y[c] = f2bf((v[j] - mean) * inv * g[c] + b[c]);
    }
}

// ---------------------------------------------------------------------------
// Per-(b,h) V mean (fully-masked fallback). One 1024-thread block per bh.
// ---------------------------------------------------------------------------
__global__ __launch_bounds__(1024)
void vmean_k(const ushort_t* __restrict__ qkv, float* __restrict__ vm) {
    __shared__ float red[16][64];
    const int bh = blockIdx.x, b = bh >> 3, h = bh & 7;
    const int wid = threadIdx.x >> 6, lane = threadIdx.x & 63;
    const ushort_t* Vb = qkv + (size_t)(b * T_SEQ) * 1536 + 1024 + h * 64 + lane;
    float s = 0.f;
    for (int t = wid; t < T_SEQ; t += 16) s += bf2f(Vb[(size_t)t * 1536]);
    red[wid][lane] = s;
    __syncthreads();
    if (wid == 0) {
        float tot = 0.f;
#pragma unroll
        for (int i = 0; i < 16; ++i) tot += red[i][lane];
        vm[bh * 64 + lane] = tot * (1.0f / T_SEQ);
    }
}

// ---------------------------------------------------------------------------
// Attention (bf16 QKV fused buffer). One wave per (b,h,q) row.
// Allowed keys: |q-k|<=128 AND (k<lo OR k>=hi). nt==0 -> vmean.
// ---------------------------------------------------------------------------
__global__ __launch_bounds__(256)
void attn_k(const ushort_t* __restrict__ qkv, const float* __restrict__ vm,
            ushort_t* __restrict__ attout, int lo, int hi) {
    __shared__ float qs[4][64];
    __shared__ float ps[4][264];
    const int lane = threadIdx.x & 63, wid = threadIdx.x >> 6;
    const int h = blockIdx.y, b = blockIdx.z;
    const int qrow = blockIdx.x * 4 + wid;
    const size_t rbase = (size_t)(b * T_SEQ) * 1536;

    qs[wid][lane] = bf2f(qkv[rbase + (size_t)qrow * 1536 + h * 64 + lane]);
    __syncthreads();

    const int w0 = max(0, qrow - THRW), w1 = min(T_SEQ - 1, qrow + THRW);
    const int a0 = w0, a1 = min(w1, lo - 1);
    const int b0 = max(w0, hi), b1 = w1;
    const int n1 = max(0, a1 - a0 + 1);
    const int n2 = max(0, b1 - b0 + 1);
    const int nt = n1 + n2;
    const size_t obase = (size_t)(b * T_SEQ + qrow) * DMODEL + h * 64 + lane;

    if (nt == 0) {
        attout[obase] = f2bf(vm[(b * NHEADS + h) * 64 + lane]);
        return;
    }

    float mx = -3.0e38f;
    for (int j = lane; j < nt; j += 64) {
        const int key = (j < n1) ? (a0 + j) : (b0 + (j - n1));
        const uint4* kr = (const uint4*)(qkv + rbase + (size_t)key * 1536 + 512 + h * 64);
        float dot = 0.f;
#pragma unroll
        for (int c = 0; c < 8; ++c) {
            uint4 u = kr[c];
            const float* qp = &qs[wid][8 * c];
            dot += __uint_as_float(u.x << 16) * qp[0] + __uint_as_float(u.x & 0xffff0000u) * qp[1];
            dot += __uint_as_float(u.y << 16) * qp[2] + __uint_as_float(u.y & 0xffff0000u) * qp[3];
            dot += __uint_as_float(u.z << 16) * qp[4] + __uint_as_float(u.z & 0xffff0000u) * qp[5];
            dot += __uint_as_float(u.w << 16) * qp[6] + __uint_as_float(u.w & 0xffff0000u) * qp[7];
        }
        const int dist = abs(qrow - key);
        const float sc = dot * 0.125f - (float)(dist / PERIODN);
        ps[wid][j] = sc;
        mx = fmaxf(mx, sc);
    }
#pragma unroll
    for (int o = 32; o; o >>= 1) mx = fmaxf(mx, __shfl_xor(mx, o));

    float sum = 0.f;
    for (int j = lane; j < nt; j += 64) {
        const float e = __expf(ps[wid][j] - mx);
        ps[wid][j] = e;
        sum += e;
    }
#pragma unroll
    for (int o = 32; o; o >>= 1) sum += __shfl_xor(sum, o);
    const float inv = 1.0f / sum;

    const ushort_t* Vb = qkv + rbase + 1024 + h * 64 + lane;
    float acc = 0.f;
    for (int key = a0; key <= a1; ++key) acc += ps[wid][key - a0] * bf2f(Vb[(size_t)key * 1536]);
    for (int key = b0; key <= b1; ++key) acc += ps[wid][n1 + key - b0] * bf2f(Vb[(size_t)key * 1536]);
    attout[obase] = f2bf(acc * inv);
}

// ---------------------------------------------------------------------------
// Final blend
// ---------------------------------------------------------------------------
__global__ __launch_bounds__(256)
void final_k(const float* __restrict__ motion, const float* __restrict__ xdec,
             float* __restrict__ out) {
    int idx = blockIdx.x * 256 + threadIdx.x;
    if (idx >= MROWS * DMOTION) return;
    const int row = idx >> 8;
    const int t = row % T_SEQ;
    const float mv = (t < CTXF || t == T_SEQ - 1) ? 1.0f : 0.0f;
    out[idx] = motion[idx] * mv + xdec[idx] * (1.0f - mv);
}

// ---------------------------------------------------------------------------
extern "C" void kernel_launch(void* const* d_in, const int* in_sizes, int n_in,
                              void* d_out, int out_size, void* d_ws, size_t ws_size,
                              hipStream_t stream) {
    const float* motion = (const float*)d_in[0];
    const float* traj   = (const float*)d_in[1];
    const float* me_w1  = (const float*)d_in[2];
    const float* me_b1  = (const float*)d_in[3];
    const float* me_w2  = (const float*)d_in[4];
    const float* me_b2  = (const float*)d_in[5];
    const float* wq = (const float*)d_in[6];
    const float* bq = (const float*)d_in[7];
    const float* wk = (const float*)d_in[8];
    const float* bk = (const float*)d_in[9];
    const float* wv = (const float*)d_in[10];
    const float* bv = (const float*)d_in[11];
    const float* wo = (const float*)d_in[12];
    const float* bo = (const float*)d_in[13];
    const float* ln1_g = (const float*)d_in[14];
    const float* ln1_b = (const float*)d_in[15];
    const float* ffn_w1 = (const float*)d_in[16];
    const float* ffn_b1 = (const float*)d_in[17];
    const float* ffn_w2 = (const float*)d_in[18];
    const float* ffn_b2 = (const float*)d_in[19];
    const float* ln2_g = (const float*)d_in[20];
    const float* ln2_b = (const float*)d_in[21];
    const float* fln_g = (const float*)d_in[22];
    const float* fln_b = (const float*)d_in[23];
    const float* dec_w1 = (const float*)d_in[24];
    const float* dec_b1 = (const float*)d_in[25];
    const float* dec_w2 = (const float*)d_in[26];
    const float* dec_b2 = (const float*)d_in[27];

    float* out = (float*)d_out;
    float* mask_out = out + (size_t)MROWS * DMOTION;

    char* base = (char*)d_ws;
    auto alloc = [&](size_t bytes) { char* p = base; base += (bytes + 255) & ~(size_t)255; return p; };

    ushort_t* qkvt  = (ushort_t*)alloc((size_t)NLAYERS * 1536 * 512 * 2);
    ushort_t* wot   = (ushort_t*)alloc((size_t)NLAYERS * 512 * 512 * 2);
    ushort_t* ffn1t = (ushort_t*)alloc((size_t)NLAYERS * 2048 * 512 * 2);
    ushort_t* ffn2t = (ushort_t*)alloc((size_t)NLAYERS * 512 * 2048 * 2);
    ushort_t* mew1t = (ushort_t*)alloc((size_t)512 * KIN * 2);
    ushort_t* mew2t = (ushort_t*)alloc((size_t)512 * 512 * 2);
    ushort_t* dec1t = (ushort_t*)alloc((size_t)512 * 512 * 2);
    ushort_t* dec2t = (ushort_t*)alloc((size_t)256 * 512 * 2);
    float*    bqkv  = (float*)alloc((size_t)NLAYERS * 1536 * 4);
    float*    pe15  = (float*)alloc((size_t)PERIODN * DMODEL * 4);
    float*    vm    = (float*)alloc((size_t)NB * NHEADS * 64 * 4);
    ushort_t* hin   = (ushort_t*)alloc((size_t)MROWS * KIN * 2);
    float*    x     = (float*)alloc((size_t)MROWS * DMODEL * 4);
    ushort_t* h     = (ushort_t*)alloc((size_t)MROWS * DMODEL * 2);
    ushort_t* qkv   = (ushort_t*)alloc((size_t)MROWS * 1536 * 2);
    ushort_t* ff    = (ushort_t*)alloc((size_t)MROWS * DFF * 2);
    float*    xdec  = (float*)qkv;   // alias: qkv dead after last attn

    const dim3 blk(256);
    pe_k<<<(PERIODN * DMODEL + 255) / 256, blk, 0, stream>>>(pe15);
    build_k<<<(MROWS * KIN + 255) / 256, blk, 0, stream>>>(motion, traj, hin, mask_out);

    // weight conversions (bf16, transposed to [N][K])
    tconv_qkv_k<<<dim3(16, 16, 18), blk, 0, stream>>>(wq, wk, wv, qkvt);
    tconv_k<<<dim3(16, 16, 6), blk, 0, stream>>>(wo, 512 * 512, wot, 512 * 512, 512, 512, 512);
    tconv_k<<<dim3(64, 16, 6), blk, 0, stream>>>(ffn_w1, 512 * 2048, ffn1t, 2048 * 512, 512, 2048, 512);
    tconv_k<<<dim3(16, 64, 6), blk, 0, stream>>>(ffn_w2, 2048 * 512, ffn2t, 512 * 2048, 2048, 512, 2048);
    tconv_k<<<dim3(16, 9, 1),  blk, 0, stream>>>(me_w1, 0, mew1t, 0, 262, 512, KIN);
    tconv_k<<<dim3(16, 16, 1), blk, 0, stream>>>(me_w2, 0, mew2t, 0, 512, 512, 512);
    tconv_k<<<dim3(16, 16, 1), blk, 0, stream>>>(dec_w1, 0, dec1t, 0, 512, 512, 512);
    tconv_k<<<dim3(8, 16, 1),  blk, 0, stream>>>(dec_w2, 0, dec2t, 0, 512, 256, 512);
    bcat_k<<<(NLAYERS * 1536 + 255) / 256, blk, 0, stream>>>(bq, bk, bv, bqkv);

    const dim3 g512(4, 24), g1536(12, 24), gff(16, 24), g256(2, 24);

    // motion encoder
    mgemm_k<1, false, false, true ><<<g512, blk, 0, stream>>>(hin, KIN, mew1t, me_b1, nullptr, nullptr, h, 512);
    mgemm_k<1, false, true,  false><<<g512, blk, 0, stream>>>(h, 512, mew2t, me_b2, nullptr, pe15, x, 512);

    for (int i = 0; i < NLAYERS; ++i) {
        const int lo = CTXF + THRW * i;
        const int hi = (T_SEQ - 1) - THRW * i;
        ln_k<<<MROWS / 4, blk, 0, stream>>>(x, ln1_g + i * 512, ln1_b + i * 512, h);
        mgemm_k<0, false, false, true><<<g1536, blk, 0, stream>>>(h, 512, qkvt + (size_t)i * 1536 * 512, bqkv + i * 1536, nullptr, nullptr, qkv, 1536);
        vmean_k<<<NB * NHEADS, dim3(1024), 0, stream>>>(qkv, vm);
        attn_k<<<dim3(T_SEQ / 4, NHEADS, NB), blk, 0, stream>>>(qkv, vm, h, lo, hi);
        mgemm_k<0, true, false, false><<<g512, blk, 0, stream>>>(h, 512, wot + (size_t)i * 512 * 512, bo + i * 512, x, nullptr, x, 512);
        ln_k<<<MROWS / 4, blk, 0, stream>>>(x, ln2_g + i * 512, ln2_b + i * 512, h);
        mgemm_k<2, false, false, true><<<gff, blk, 0, stream>>>(h, 512, ffn1t + (size_t)i * 2048 * 512, ffn_b1 + i * 2048, nullptr, nullptr, ff, 2048);
        mgemm_k<0, true, false, false><<<g512, blk, 0, stream>>>(ff, 2048, ffn2t + (size_t)i * 512 * 2048, ffn_b2 + i * 512, x, nullptr, x, 512);
    }

    // decoder
    ln_k<<<MROWS / 4, blk, 0, stream>>>(x, fln_g, fln_b, h);
    mgemm_k<1, false, false, true ><<<g512, blk, 0, stream>>>(h, 512, dec1t, dec_b1, nullptr, nullptr, ff, 512);
    mgemm_k<0, false, false, false><<<g256, blk, 0, stream>>>(ff, 512, dec2t, dec_b2, nullptr, nullptr, xdec, 256);

    final_k<<<(MROWS * DMOTION + 255) / 256, blk, 0, stream>>>(motion, xdec, out);
}